// Round 11
// baseline (498.306 us; speedup 1.0000x reference)
//
#include <hip/hip_runtime.h>
#include <hip/hip_bf16.h>

typedef __attribute__((ext_vector_type(4))) float f32x4;
typedef __attribute__((ext_vector_type(8))) short bfrag;   // 8 bf16 = 4 VGPRs
typedef __attribute__((ext_vector_type(4))) float facc;    // MFMA C/D
typedef __attribute__((ext_vector_type(8))) ushort u16x8;  // 16B of bf16

#define N_MOVES 200000
#define N_EDGES 1600000
#define DEMB 256
#define KD 512          // 2*D, also layer-2 K
#define H1D 512
#define H2D 256
#define MT 128          // moves per block
#define NTHREADS 1024   // 16 waves, 4/SIMD, 1 block/CU (131KB LDS)

__device__ __forceinline__ ushort f2b(float f) {   // f32 -> bf16 RNE
  union { float f; unsigned u; } x; x.f = f;
  unsigned r = (x.u + 0x7fffu + ((x.u >> 16) & 1u)) >> 16;
  return (ushort)r;
}
__device__ __forceinline__ float b2f(ushort h) {
  union { unsigned u; float f; } x; x.u = ((unsigned)h) << 16;
  return x.f;
}

// ---- prep: W1 [512,512] f32 -> bf16 ; W2 [256,512] f32 -> bf16 (into ws) ----
__global__ void convert_w(const float* __restrict__ W1, const float* __restrict__ W2,
                          ushort* __restrict__ Wb) {
  int i = (blockIdx.x * 256 + threadIdx.x) * 4;
  const int n1 = H1D * KD;  // 262144
  if (i < n1) {
    f32x4 v = *(const f32x4*)(W1 + i);
    ushort4 h = { f2b(v.x), f2b(v.y), f2b(v.z), f2b(v.w) };
    *(ushort4*)(Wb + i) = h;
  } else {
    int j = i - n1;          // < 131072
    f32x4 v = *(const f32x4*)(W2 + j);
    ushort4 h = { f2b(v.x), f2b(v.y), f2b(v.z), f2b(v.w) };
    *(ushort4*)(Wb + n1 + j) = h;
  }
}

// ---- prep: embedding table f32 -> bf16 (25.6M elems) ----
__global__ void convert_emb(const float* __restrict__ E, ushort* __restrict__ Eb) {
  int i = (blockIdx.x * 256 + threadIdx.x) * 8;
  f32x4 a = *(const f32x4*)(E + i);
  f32x4 b = *(const f32x4*)(E + i + 4);
  u16x8 h = { f2b(a.x), f2b(a.y), f2b(a.z), f2b(a.w),
              f2b(b.x), f2b(b.y), f2b(b.z), f2b(b.w) };
  *(u16x8*)(Eb + i) = h;
}

// ---- fused gather + 3-layer MLP, MT=128, in-place LDS, swapped-operand MFMA ----
// Register discipline: NOTHING extra lives across the K-loops.
// K-loop peak = acc(64) + aE(32) + bA/bB(16) + wp(4) + misc(~8) < 128.
template<int EMBBF>
__global__ __launch_bounds__(NTHREADS, 4)    // 4 waves/SIMD -> 128 unified regs/wave
void fused_mlp(const float* __restrict__ emb,        // f32 table (fallback)
               const ushort* __restrict__ embb,      // bf16 table (fast path)
               const int* __restrict__ edge_index,   // [2][N_EDGES]
               const int* __restrict__ move_idx,     // [N_MOVES]
               const ushort* __restrict__ W1b,       // [512][512] bf16
               const float* __restrict__ b1,
               const ushort* __restrict__ W2b,       // [256][512] bf16
               const float* __restrict__ b2,
               const float* __restrict__ W3,         // [256] f32
               const float* __restrict__ b3,
               float* __restrict__ out)
{
  __shared__ ushort bufA[MT][KD];   // 128KB: X -> H1 (in place) -> H2 (first 64KB)
  __shared__ int   s_src[MT], s_tgt[MT];
  __shared__ float sW3[H2D];

  const int tid  = threadIdx.x;
  const int lane = tid & 63;
  const int wave = tid >> 6;        // 0..15
  const int m0   = blockIdx.x * MT;

  if (tid < MT) {
    int mi = m0 + tid;
    if (mi >= N_MOVES) mi = N_MOVES - 1;   // tail-block clamp (harmless dup work)
    int e = move_idx[mi];
    s_src[tid] = edge_index[e];
    s_tgt[tid] = edge_index[N_EDGES + e];
  }
  if (tid < H2D) sW3[tid] = W3[tid];
  __syncthreads();

  const int arow = lane & 15;            // fragment row index
  const int akB  = (lane >> 4) << 4;     // k chunk base, bytes
  const int nq   = (lane >> 4) << 2;     // out-col quad base (swapped D)

  // W1: wave owns 32 out-cols (2 n-groups)
  const ushort* wp0 = W1b + (size_t)(((wave << 5) + arow) * KD) + (akB >> 1);
  const ushort* wp1 = wp0 + 16 * KD;

  // ---- W1 ping-pong prologue (kk=0 -> bA, kk=1 -> bB): in flight during gather ----
  bfrag bA[2], bB[2];
  bA[0] = *(const bfrag*)(wp0);      bA[1] = *(const bfrag*)(wp1);
  bB[0] = *(const bfrag*)(wp0 + 32); bB[1] = *(const bfrag*)(wp1 + 32);

  // ---- gather: X[row] = concat(emb[src], emb[tgt]) bf16 ----
  if (EMBBF) {
    #pragma unroll
    for (int it = 0; it < 8; ++it) {
      int row  = (wave << 3) + it;             // 16 waves x 8 = 128 rows
      int gl   = lane ^ (row & 7);             // involution, matches read swizzle
      int node = (gl < 32) ? s_src[row] : s_tgt[row];
      const ushort* gp = embb + (size_t)node * DEMB + ((size_t)(gl & 31) << 3);
      __builtin_amdgcn_global_load_lds(
          (const __attribute__((address_space(1))) void*)gp,
          (__attribute__((address_space(3))) void*)(&bufA[row][0]),
          16, 0, 0);
    }
  } else {
    for (int u = tid; u < MT * 128; u += NTHREADS) {
      int row = u >> 7;
      int c4  = u & 127;
      const float* sp = (c4 < 64) ? (emb + (size_t)s_src[row] * DEMB + (c4 << 2))
                                  : (emb + (size_t)s_tgt[row] * DEMB + ((c4 - 64) << 2));
      f32x4 v = *(const f32x4*)sp;
      ushort4 h = { f2b(v.x), f2b(v.y), f2b(v.z), f2b(v.w) };
      int bo = (c4 << 3) ^ ((row & 7) << 4);
      *(ushort4*)((char*)(&bufA[row][0]) + bo) = h;
    }
  }
  __syncthreads();   // X ready

  // ================= layer 1: H1[128][512] = relu(X @ W1^T + b1) =================
  // swapped operands: acc reg-dim = out-col quad, lane&15 = move row. Bias in epilogue.
  facc acc[8][2];
  #pragma unroll
  for (int mg = 0; mg < 8; ++mg) {
    acc[mg][0] = (facc){0.f, 0.f, 0.f, 0.f};
    acc[mg][1] = (facc){0.f, 0.f, 0.f, 0.f};
  }

  bfrag aE[8];
  #pragma unroll
  for (int mg = 0; mg < 8; ++mg) {   // A for kk=0 (8 pipelined ds_reads)
    int row = (mg << 4) + arow;
    int bo = akB ^ ((row & 7) << 4);
    aE[mg] = *(const bfrag*)((const char*)(&bufA[row][0]) + bo);
  }

  #pragma unroll
  for (int kk2 = 0; kk2 < 8; ++kk2) {
    const int kk = kk2 << 1;
    // even cluster: (bA, aE[kk])
    __builtin_amdgcn_s_setprio(1);
    #pragma unroll
    for (int mg = 0; mg < 8; ++mg) {
      acc[mg][0] = __builtin_amdgcn_mfma_f32_16x16x32_bf16(bA[0], aE[mg], acc[mg][0], 0, 0, 0);
      acc[mg][1] = __builtin_amdgcn_mfma_f32_16x16x32_bf16(bA[1], aE[mg], acc[mg][1], 0, 0, 0);
    }
    __builtin_amdgcn_s_setprio(0);
    #pragma unroll
    for (int mg = 0; mg < 8; ++mg) {   // A for kk+1
      int row = (mg << 4) + arow;
      int bo = (((kk + 1) << 6) + akB) ^ ((row & 7) << 4);
      aE[mg] = *(const bfrag*)((const char*)(&bufA[row][0]) + bo);
    }
    if (kk + 2 < 16) {                 // refill bA for kk+2
      bA[0] = *(const bfrag*)(wp0 + ((kk + 2) << 5));
      bA[1] = *(const bfrag*)(wp1 + ((kk + 2) << 5));
    }
    // odd cluster: (bB, aE[kk+1])
    __builtin_amdgcn_s_setprio(1);
    #pragma unroll
    for (int mg = 0; mg < 8; ++mg) {
      acc[mg][0] = __builtin_amdgcn_mfma_f32_16x16x32_bf16(bB[0], aE[mg], acc[mg][0], 0, 0, 0);
      acc[mg][1] = __builtin_amdgcn_mfma_f32_16x16x32_bf16(bB[1], aE[mg], acc[mg][1], 0, 0, 0);
    }
    __builtin_amdgcn_s_setprio(0);
    if (kk2 < 7) {
      #pragma unroll
      for (int mg = 0; mg < 8; ++mg) {   // A for kk+2
        int row = (mg << 4) + arow;
        int bo = (((kk + 2) << 6) + akB) ^ ((row & 7) << 4);
        aE[mg] = *(const bfrag*)((const char*)(&bufA[row][0]) + bo);
      }
      if (kk + 3 < 16) {               // refill bB for kk+3
        bB[0] = *(const bfrag*)(wp0 + ((kk + 3) << 5));
        bB[1] = *(const bfrag*)(wp1 + ((kk + 3) << 5));
      }
    }
  }

  // ---- post-K-loop transients: bias1/2, W2 prologue (overlap the barrier) ----
  const ushort* cp0 = W2b + (size_t)(((wave << 4) + arow) * KD) + (akB >> 1);
  bfrag cA = *(const bfrag*)(cp0);
  bfrag cB = *(const bfrag*)(cp0 + 32);
  f32x4 bv1[2];
  bv1[0] = *(const f32x4*)(b1 + (wave << 5) + nq);
  bv1[1] = *(const f32x4*)(b1 + (wave << 5) + 16 + nq);

  __syncthreads();   // all X reads done -> safe to overwrite bufA with H1

  // epilogue 1: +bias, relu, ->bf16, packed 8B writes into bufA (H1, swizzled)
  #pragma unroll
  for (int mg = 0; mg < 8; ++mg) {
    int m = (mg << 4) + arow;
    #pragma unroll
    for (int ng = 0; ng < 2; ++ng) {
      int nb = (wave << 5) + (ng << 4) + nq;     // 4 consecutive out-cols
      ushort4 h;
      h.x = f2b(fmaxf(acc[mg][ng][0] + bv1[ng][0], 0.f));
      h.y = f2b(fmaxf(acc[mg][ng][1] + bv1[ng][1], 0.f));
      h.z = f2b(fmaxf(acc[mg][ng][2] + bv1[ng][2], 0.f));
      h.w = f2b(fmaxf(acc[mg][ng][3] + bv1[ng][3], 0.f));
      int bo = (nb << 1) ^ ((m & 7) << 4);
      *(ushort4*)((char*)(&bufA[0][0]) + m * (KD * 2) + bo) = h;
    }
  }
  __syncthreads();   // H1 ready

  // ================= layer 2: H2[128][256] = relu(H1 @ W2^T + b2) =================
  facc acc2[8];
  #pragma unroll
  for (int mg = 0; mg < 8; ++mg) acc2[mg] = (facc){0.f, 0.f, 0.f, 0.f};

  #pragma unroll
  for (int mg = 0; mg < 8; ++mg) {   // A for kk=0 (H1)
    int row = (mg << 4) + arow;
    int bo = akB ^ ((row & 7) << 4);
    aE[mg] = *(const bfrag*)((const char*)(&bufA[row][0]) + bo);
  }

  #pragma unroll
  for (int kk2 = 0; kk2 < 8; ++kk2) {
    const int kk = kk2 << 1;
    __builtin_amdgcn_s_setprio(1);
    #pragma unroll
    for (int mg = 0; mg < 8; ++mg)
      acc2[mg] = __builtin_amdgcn_mfma_f32_16x16x32_bf16(cA, aE[mg], acc2[mg], 0, 0, 0);
    __builtin_amdgcn_s_setprio(0);
    #pragma unroll
    for (int mg = 0; mg < 8; ++mg) {
      int row = (mg << 4) + arow;
      int bo = (((kk + 1) << 6) + akB) ^ ((row & 7) << 4);
      aE[mg] = *(const bfrag*)((const char*)(&bufA[row][0]) + bo);
    }
    if (kk + 2 < 16) cA = *(const bfrag*)(cp0 + ((kk + 2) << 5));
    __builtin_amdgcn_s_setprio(1);
    #pragma unroll
    for (int mg = 0; mg < 8; ++mg)
      acc2[mg] = __builtin_amdgcn_mfma_f32_16x16x32_bf16(cB, aE[mg], acc2[mg], 0, 0, 0);
    __builtin_amdgcn_s_setprio(0);
    if (kk2 < 7) {
      #pragma unroll
      for (int mg = 0; mg < 8; ++mg) {
        int row = (mg << 4) + arow;
        int bo = (((kk + 2) << 6) + akB) ^ ((row & 7) << 4);
        aE[mg] = *(const bfrag*)((const char*)(&bufA[row][0]) + bo);
      }
      if (kk + 3 < 16) cB = *(const bfrag*)(cp0 + ((kk + 3) << 5));
    }
  }

  f32x4 bv2 = *(const f32x4*)(b2 + (wave << 4) + nq);   // transient

  __syncthreads();   // all H1 reads done -> safe to overwrite with H2

  // epilogue 2: H2 overlays first 64KB of bufA
  ushort (*H2s)[H2D] = (ushort(*)[H2D])bufA;
  #pragma unroll
  for (int mg = 0; mg < 8; ++mg) {
    int m = (mg << 4) + arow;
    int nb = (wave << 4) + nq;
    ushort4 h;
    h.x = f2b(fmaxf(acc2[mg][0] + bv2[0], 0.f));
    h.y = f2b(fmaxf(acc2[mg][1] + bv2[1], 0.f));
    h.z = f2b(fmaxf(acc2[mg][2] + bv2[2], 0.f));
    h.w = f2b(fmaxf(acc2[mg][3] + bv2[3], 0.f));
    int bo = (nb << 1) ^ ((m & 7) << 4);
    *(ushort4*)((char*)(&H2s[0][0]) + m * (H2D * 2) + bo) = h;
  }
  __syncthreads();   // H2 ready

  // ================= layer 3: out[m] = H2[m] . W3 + b3 (8 lanes per move) =================
  {
    const float b3v = b3[0];
    int row = tid >> 3;          // 0..127
    int oct = tid & 7;           // 32 k's each
    float sum = 0.f;
    #pragma unroll
    for (int j = 0; j < 4; ++j) {
      int kb = (oct << 6) + (j << 4);                 // byte offset of k*2
      int bo = kb ^ ((row & 7) << 4);
      bfrag hv = *(const bfrag*)((const char*)(&H2s[row][0]) + bo);
      int k0 = (oct << 5) + (j << 3);
      #pragma unroll
      for (int e = 0; e < 8; ++e)
        sum += b2f((ushort)hv[e]) * sW3[k0 + e];
    }
    sum += __shfl_xor(sum, 1);
    sum += __shfl_xor(sum, 2);
    sum += __shfl_xor(sum, 4);
    if (oct == 0 && (m0 + row) < N_MOVES) out[m0 + row] = sum + b3v;
  }
}

extern "C" void kernel_launch(void* const* d_in, const int* in_sizes, int n_in,
                              void* d_out, int out_size, void* d_ws, size_t ws_size,
                              hipStream_t stream) {
  const float* emb        = (const float*)d_in[0];
  const int*   edge_index = (const int*)d_in[1];
  const int*   move_idx   = (const int*)d_in[2];
  const float* W1         = (const float*)d_in[3];
  const float* b1         = (const float*)d_in[4];
  const float* W2         = (const float*)d_in[5];
  const float* b2         = (const float*)d_in[6];
  const float* W3         = (const float*)d_in[7];
  const float* b3         = (const float*)d_in[8];
  float* out = (float*)d_out;

  ushort* Wb   = (ushort*)d_ws;                 // W1b [512*512] + W2b [256*512]
  ushort* Embb = Wb + (H1D * KD + H2D * KD);    // bf16 emb table [100000*256]
  const size_t need = (size_t)(H1D * KD + H2D * KD + 100000 * DEMB) * 2;
  const int grid = (N_MOVES + MT - 1) / MT;     // 1563 (tail guarded)

  convert_w<<<384, 256, 0, stream>>>(W1, W2, Wb);

  if (ws_size >= need) {
    convert_emb<<<12500, 256, 0, stream>>>(emb, Embb);
    fused_mlp<1><<<grid, NTHREADS, 0, stream>>>(
        emb, Embb, edge_index, move_idx,
        Wb, b1, Wb + H1D * KD, b2, W3, b3, out);
  } else {
    fused_mlp<0><<<grid, NTHREADS, 0, stream>>>(
        emb, Embb, edge_index, move_idx,
        Wb, b1, Wb + H1D * KD, b2, W3, b3, out);
  }
}

// Round 12
// 457.253 us; speedup vs baseline: 1.0898x; 1.0898x over previous
//
#include <hip/hip_runtime.h>
#include <hip/hip_bf16.h>

typedef __attribute__((ext_vector_type(4))) float f32x4;
typedef __attribute__((ext_vector_type(8))) short bfrag;   // 8 bf16 = 4 VGPRs
typedef __attribute__((ext_vector_type(4))) float facc;    // MFMA C/D
typedef __attribute__((ext_vector_type(8))) ushort u16x8;  // 16B of bf16

#define N_MOVES 200000
#define N_EDGES 1600000
#define DEMB 256
#define KD 512          // 2*D, also layer-2 K
#define H1D 512
#define H2D 256
#define MT 128          // moves per block (131 FLOP per weight-byte -> L2 feasible)
#define NTHREADS 512    // 8 waves, 1 block/CU, 256 unified regs/wave

__device__ __forceinline__ ushort f2b(float f) {   // f32 -> bf16 RNE
  union { float f; unsigned u; } x; x.f = f;
  unsigned r = (x.u + 0x7fffu + ((x.u >> 16) & 1u)) >> 16;
  return (ushort)r;
}
__device__ __forceinline__ float b2f(ushort h) {
  union { unsigned u; float f; } x; x.u = ((unsigned)h) << 16;
  return x.f;
}

// ---- prep: W1 [512,512] f32 -> bf16 ; W2 [256,512] f32 -> bf16 (into ws) ----
__global__ void convert_w(const float* __restrict__ W1, const float* __restrict__ W2,
                          ushort* __restrict__ Wb) {
  int i = (blockIdx.x * 256 + threadIdx.x) * 4;
  const int n1 = H1D * KD;  // 262144
  if (i < n1) {
    f32x4 v = *(const f32x4*)(W1 + i);
    ushort4 h = { f2b(v.x), f2b(v.y), f2b(v.z), f2b(v.w) };
    *(ushort4*)(Wb + i) = h;
  } else {
    int j = i - n1;          // < 131072
    f32x4 v = *(const f32x4*)(W2 + j);
    ushort4 h = { f2b(v.x), f2b(v.y), f2b(v.z), f2b(v.w) };
    *(ushort4*)(Wb + n1 + j) = h;
  }
}

// ---- prep: embedding table f32 -> bf16 (25.6M elems) ----
__global__ void convert_emb(const float* __restrict__ E, ushort* __restrict__ Eb) {
  int i = (blockIdx.x * 256 + threadIdx.x) * 8;
  f32x4 a = *(const f32x4*)(E + i);
  f32x4 b = *(const f32x4*)(E + i + 4);
  u16x8 h = { f2b(a.x), f2b(a.y), f2b(a.z), f2b(a.w),
              f2b(b.x), f2b(b.y), f2b(b.z), f2b(b.w) };
  *(u16x8*)(Eb + i) = h;
}

// ---- fused gather + 3-layer MLP: MT=128, 8 waves, 256-reg budget ----
// K-loop peak: acc 128 + aE 32 + bA/bB 32 + addr ~15 ~= 210 < 256 (R8-proven headroom).
template<int EMBBF>
__global__ __launch_bounds__(NTHREADS, 2)    // 2 waves/SIMD min -> 256 regs/wave
void fused_mlp(const float* __restrict__ emb,        // f32 table (fallback)
               const ushort* __restrict__ embb,      // bf16 table (fast path)
               const int* __restrict__ edge_index,   // [2][N_EDGES]
               const int* __restrict__ move_idx,     // [N_MOVES]
               const ushort* __restrict__ W1b,       // [512][512] bf16
               const float* __restrict__ b1,
               const ushort* __restrict__ W2b,       // [256][512] bf16
               const float* __restrict__ b2,
               const float* __restrict__ W3,         // [256] f32
               const float* __restrict__ b3,
               float* __restrict__ out)
{
  __shared__ ushort bufA[MT][KD];   // 128KB: X -> H1 (in place) -> H2 (first 64KB)
  __shared__ int   s_src[MT], s_tgt[MT];
  __shared__ float sW3[H2D];

  const int tid  = threadIdx.x;
  const int lane = tid & 63;
  const int wave = tid >> 6;        // 0..7
  const int m0   = blockIdx.x * MT;

  if (tid < MT) {
    int mi = m0 + tid;
    if (mi >= N_MOVES) mi = N_MOVES - 1;   // tail-block clamp (harmless dup work)
    int e = move_idx[mi];
    s_src[tid] = edge_index[e];
    s_tgt[tid] = edge_index[N_EDGES + e];
  }
  if (tid < H2D) sW3[tid] = W3[tid];
  __syncthreads();

  const int arow = lane & 15;            // fragment row index
  const int akB  = (lane >> 4) << 4;     // k chunk base, bytes
  const int nq   = (lane >> 4) << 2;     // out-col quad base (swapped D)

  // W1: wave owns 64 out-cols (4 n-groups)
  const ushort* wp0 = W1b + (size_t)(((wave << 6) + arow) * KD) + (akB >> 1);
  const ushort* wp1 = wp0 + 16 * KD;
  const ushort* wp2 = wp0 + 32 * KD;
  const ushort* wp3 = wp0 + 48 * KD;

  // ---- W1 ping-pong prologue (kk=0 -> bA, kk=1 -> bB): in flight during gather ----
  bfrag bA[4], bB[4];
  bA[0] = *(const bfrag*)(wp0);      bA[1] = *(const bfrag*)(wp1);
  bA[2] = *(const bfrag*)(wp2);      bA[3] = *(const bfrag*)(wp3);
  bB[0] = *(const bfrag*)(wp0 + 32); bB[1] = *(const bfrag*)(wp1 + 32);
  bB[2] = *(const bfrag*)(wp2 + 32); bB[3] = *(const bfrag*)(wp3 + 32);

  // ---- gather: X[row] = concat(emb[src], emb[tgt]) bf16 ----
  if (EMBBF) {
    #pragma unroll
    for (int it = 0; it < 16; ++it) {
      int row  = (wave << 4) + it;             // 8 waves x 16 = 128 rows
      int gl   = lane ^ (row & 7);             // involution, matches read swizzle
      int node = (gl < 32) ? s_src[row] : s_tgt[row];
      const ushort* gp = embb + (size_t)node * DEMB + ((size_t)(gl & 31) << 3);
      __builtin_amdgcn_global_load_lds(
          (const __attribute__((address_space(1))) void*)gp,
          (__attribute__((address_space(3))) void*)(&bufA[row][0]),
          16, 0, 0);
    }
  } else {
    for (int u = tid; u < MT * 128; u += NTHREADS) {
      int row = u >> 7;
      int c4  = u & 127;
      const float* sp = (c4 < 64) ? (emb + (size_t)s_src[row] * DEMB + (c4 << 2))
                                  : (emb + (size_t)s_tgt[row] * DEMB + ((c4 - 64) << 2));
      f32x4 v = *(const f32x4*)sp;
      ushort4 h = { f2b(v.x), f2b(v.y), f2b(v.z), f2b(v.w) };
      int bo = (c4 << 3) ^ ((row & 7) << 4);
      *(ushort4*)((char*)(&bufA[row][0]) + bo) = h;
    }
  }
  __syncthreads();   // X ready

  // ================= layer 1: H1[128][512] = relu(X @ W1^T + b1) =================
  // swapped operands: acc reg-dim = out-col quad, lane&15 = move row.
  facc acc[8][4];
  #pragma unroll
  for (int mg = 0; mg < 8; ++mg)
    #pragma unroll
    for (int ng = 0; ng < 4; ++ng)
      acc[mg][ng] = (facc){0.f, 0.f, 0.f, 0.f};

  bfrag aE[8];
  #pragma unroll
  for (int mg = 0; mg < 8; ++mg) {   // A for kk=0 (8 pipelined ds_reads)
    int row = (mg << 4) + arow;
    int bo = akB ^ ((row & 7) << 4);
    aE[mg] = *(const bfrag*)((const char*)(&bufA[row][0]) + bo);
  }

  #pragma unroll
  for (int kk2 = 0; kk2 < 8; ++kk2) {
    const int kk = kk2 << 1;
    // even cluster: (bA, aE[kk]) -> 32 MFMAs
    __builtin_amdgcn_s_setprio(1);
    #pragma unroll
    for (int mg = 0; mg < 8; ++mg)
      #pragma unroll
      for (int ng = 0; ng < 4; ++ng)
        acc[mg][ng] = __builtin_amdgcn_mfma_f32_16x16x32_bf16(bA[ng], aE[mg], acc[mg][ng], 0, 0, 0);
    __builtin_amdgcn_s_setprio(0);
    #pragma unroll
    for (int mg = 0; mg < 8; ++mg) {   // A for kk+1
      int row = (mg << 4) + arow;
      int bo = (((kk + 1) << 6) + akB) ^ ((row & 7) << 4);
      aE[mg] = *(const bfrag*)((const char*)(&bufA[row][0]) + bo);
    }
    if (kk + 2 < 16) {                 // refill bA for kk+2
      bA[0] = *(const bfrag*)(wp0 + ((kk + 2) << 5));
      bA[1] = *(const bfrag*)(wp1 + ((kk + 2) << 5));
      bA[2] = *(const bfrag*)(wp2 + ((kk + 2) << 5));
      bA[3] = *(const bfrag*)(wp3 + ((kk + 2) << 5));
    }
    // odd cluster: (bB, aE[kk+1]) -> 32 MFMAs
    __builtin_amdgcn_s_setprio(1);
    #pragma unroll
    for (int mg = 0; mg < 8; ++mg)
      #pragma unroll
      for (int ng = 0; ng < 4; ++ng)
        acc[mg][ng] = __builtin_amdgcn_mfma_f32_16x16x32_bf16(bB[ng], aE[mg], acc[mg][ng], 0, 0, 0);
    __builtin_amdgcn_s_setprio(0);
    if (kk2 < 7) {
      #pragma unroll
      for (int mg = 0; mg < 8; ++mg) {   // A for kk+2
        int row = (mg << 4) + arow;
        int bo = (((kk + 2) << 6) + akB) ^ ((row & 7) << 4);
        aE[mg] = *(const bfrag*)((const char*)(&bufA[row][0]) + bo);
      }
      if (kk + 3 < 16) {               // refill bB for kk+3
        bB[0] = *(const bfrag*)(wp0 + ((kk + 3) << 5));
        bB[1] = *(const bfrag*)(wp1 + ((kk + 3) << 5));
        bB[2] = *(const bfrag*)(wp2 + ((kk + 3) << 5));
        bB[3] = *(const bfrag*)(wp3 + ((kk + 3) << 5));
      }
    }
  }

  // ---- post-K-loop transients: W2 prologue + bias1 (land across the barrier) ----
  const ushort* cp0 = W2b + (size_t)(((wave << 5) + arow) * KD) + (akB >> 1);  // 32 cols/wave
  const ushort* cp1 = cp0 + 16 * KD;
  bfrag cA[2], cB[2];
  cA[0] = *(const bfrag*)(cp0);      cA[1] = *(const bfrag*)(cp1);
  cB[0] = *(const bfrag*)(cp0 + 32); cB[1] = *(const bfrag*)(cp1 + 32);
  f32x4 bv1[4];
  #pragma unroll
  for (int ng = 0; ng < 4; ++ng)
    bv1[ng] = *(const f32x4*)(b1 + (wave << 6) + (ng << 4) + nq);

  __syncthreads();   // all X reads done -> safe to overwrite bufA with H1

  // epilogue 1: +bias, relu, ->bf16, packed 8B writes into bufA (H1, swizzled)
  #pragma unroll
  for (int mg = 0; mg < 8; ++mg) {
    int m = (mg << 4) + arow;
    #pragma unroll
    for (int ng = 0; ng < 4; ++ng) {
      int nb = (wave << 6) + (ng << 4) + nq;     // 4 consecutive out-cols
      ushort4 h;
      h.x = f2b(fmaxf(acc[mg][ng][0] + bv1[ng][0], 0.f));
      h.y = f2b(fmaxf(acc[mg][ng][1] + bv1[ng][1], 0.f));
      h.z = f2b(fmaxf(acc[mg][ng][2] + bv1[ng][2], 0.f));
      h.w = f2b(fmaxf(acc[mg][ng][3] + bv1[ng][3], 0.f));
      int bo = (nb << 1) ^ ((m & 7) << 4);
      *(ushort4*)((char*)(&bufA[0][0]) + m * (KD * 2) + bo) = h;
    }
  }
  __syncthreads();   // H1 ready

  // ================= layer 2: H2[128][256] = relu(H1 @ W2^T + b2) =================
  facc acc2[8][2];
  #pragma unroll
  for (int mg = 0; mg < 8; ++mg) {
    acc2[mg][0] = (facc){0.f, 0.f, 0.f, 0.f};
    acc2[mg][1] = (facc){0.f, 0.f, 0.f, 0.f};
  }

  #pragma unroll
  for (int mg = 0; mg < 8; ++mg) {   // A for kk=0 (H1)
    int row = (mg << 4) + arow;
    int bo = akB ^ ((row & 7) << 4);
    aE[mg] = *(const bfrag*)((const char*)(&bufA[row][0]) + bo);
  }

  #pragma unroll
  for (int kk2 = 0; kk2 < 8; ++kk2) {
    const int kk = kk2 << 1;
    __builtin_amdgcn_s_setprio(1);
    #pragma unroll
    for (int mg = 0; mg < 8; ++mg) {
      acc2[mg][0] = __builtin_amdgcn_mfma_f32_16x16x32_bf16(cA[0], aE[mg], acc2[mg][0], 0, 0, 0);
      acc2[mg][1] = __builtin_amdgcn_mfma_f32_16x16x32_bf16(cA[1], aE[mg], acc2[mg][1], 0, 0, 0);
    }
    __builtin_amdgcn_s_setprio(0);
    #pragma unroll
    for (int mg = 0; mg < 8; ++mg) {   // A for kk+1
      int row = (mg << 4) + arow;
      int bo = (((kk + 1) << 6) + akB) ^ ((row & 7) << 4);
      aE[mg] = *(const bfrag*)((const char*)(&bufA[row][0]) + bo);
    }
    if (kk + 2 < 16) {
      cA[0] = *(const bfrag*)(cp0 + ((kk + 2) << 5));
      cA[1] = *(const bfrag*)(cp1 + ((kk + 2) << 5));
    }
    __builtin_amdgcn_s_setprio(1);
    #pragma unroll
    for (int mg = 0; mg < 8; ++mg) {
      acc2[mg][0] = __builtin_amdgcn_mfma_f32_16x16x32_bf16(cB[0], aE[mg], acc2[mg][0], 0, 0, 0);
      acc2[mg][1] = __builtin_amdgcn_mfma_f32_16x16x32_bf16(cB[1], aE[mg], acc2[mg][1], 0, 0, 0);
    }
    __builtin_amdgcn_s_setprio(0);
    if (kk2 < 7) {
      #pragma unroll
      for (int mg = 0; mg < 8; ++mg) {   // A for kk+2
        int row = (mg << 4) + arow;
        int bo = (((kk + 2) << 6) + akB) ^ ((row & 7) << 4);
        aE[mg] = *(const bfrag*)((const char*)(&bufA[row][0]) + bo);
      }
      if (kk + 3 < 16) {
        cB[0] = *(const bfrag*)(cp0 + ((kk + 3) << 5));
        cB[1] = *(const bfrag*)(cp1 + ((kk + 3) << 5));
      }
    }
  }

  f32x4 bv2[2];   // transient
  bv2[0] = *(const f32x4*)(b2 + (wave << 5) + nq);
  bv2[1] = *(const f32x4*)(b2 + (wave << 5) + 16 + nq);

  __syncthreads();   // all H1 reads done -> safe to overwrite with H2

  // epilogue 2: H2 overlays first 64KB of bufA
  ushort (*H2s)[H2D] = (ushort(*)[H2D])bufA;
  #pragma unroll
  for (int mg = 0; mg < 8; ++mg) {
    int m = (mg << 4) + arow;
    #pragma unroll
    for (int ng = 0; ng < 2; ++ng) {
      int nb = (wave << 5) + (ng << 4) + nq;
      ushort4 h;
      h.x = f2b(fmaxf(acc2[mg][ng][0] + bv2[ng][0], 0.f));
      h.y = f2b(fmaxf(acc2[mg][ng][1] + bv2[ng][1], 0.f));
      h.z = f2b(fmaxf(acc2[mg][ng][2] + bv2[ng][2], 0.f));
      h.w = f2b(fmaxf(acc2[mg][ng][3] + bv2[ng][3], 0.f));
      int bo = (nb << 1) ^ ((m & 7) << 4);
      *(ushort4*)((char*)(&H2s[0][0]) + m * (H2D * 2) + bo) = h;
    }
  }
  __syncthreads();   // H2 ready

  // ================= layer 3: out[m] = H2[m] . W3 + b3 (4 lanes per move) =================
  {
    const float b3v = b3[0];
    int row = tid >> 2;          // 0..127
    int oct = tid & 3;           // 64 k's each
    float sum = 0.f;
    #pragma unroll
    for (int j = 0; j < 8; ++j) {
      int kb = (oct << 7) + (j << 4);                 // byte offset of k*2
      int bo = kb ^ ((row & 7) << 4);
      bfrag hv = *(const bfrag*)((const char*)(&H2s[row][0]) + bo);
      int k0 = (oct << 6) + (j << 3);
      #pragma unroll
      for (int e = 0; e < 8; ++e)
        sum += b2f((ushort)hv[e]) * sW3[k0 + e];
    }
    sum += __shfl_xor(sum, 1);
    sum += __shfl_xor(sum, 2);
    if (oct == 0 && (m0 + row) < N_MOVES) out[m0 + row] = sum + b3v;
  }
}

extern "C" void kernel_launch(void* const* d_in, const int* in_sizes, int n_in,
                              void* d_out, int out_size, void* d_ws, size_t ws_size,
                              hipStream_t stream) {
  const float* emb        = (const float*)d_in[0];
  const int*   edge_index = (const int*)d_in[1];
  const int*   move_idx   = (const int*)d_in[2];
  const float* W1         = (const float*)d_in[3];
  const float* b1         = (const float*)d_in[4];
  const float* W2         = (const float*)d_in[5];
  const float* b2         = (const float*)d_in[6];
  const float* W3         = (const float*)d_in[7];
  const float* b3         = (const float*)d_in[8];
  float* out = (float*)d_out;

  ushort* Wb   = (ushort*)d_ws;                 // W1b [512*512] + W2b [256*512]
  ushort* Embb = Wb + (H1D * KD + H2D * KD);    // bf16 emb table [100000*256]
  const size_t need = (size_t)(H1D * KD + H2D * KD + 100000 * DEMB) * 2;
  const int grid = (N_MOVES + MT - 1) / MT;     // 1563 (tail guarded)

  convert_w<<<384, 256, 0, stream>>>(W1, W2, Wb);

  if (ws_size >= need) {
    convert_emb<<<12500, 256, 0, stream>>>(emb, Embb);
    fused_mlp<1><<<grid, NTHREADS, 0, stream>>>(
        emb, Embb, edge_index, move_idx,
        Wb, b1, Wb + H1D * KD, b2, W3, b3, out);
  } else {
    fused_mlp<0><<<grid, NTHREADS, 0, stream>>>(
        emb, Embb, edge_index, move_idx,
        Wb, b1, Wb + H1D * KD, b2, W3, b3, out);
  }
}